// Round 6
// baseline (138.496 us; speedup 1.0000x reference)
//
#include <hip/hip_runtime.h>

#define NB 8
#define NC 256
#define FH 64
#define FW 64
#define NS (FH * FW)          // 4096 spatial positions per batch
#define NSAMP 131072
#define MARGIN_F 12.0f
#define GATHER_BLOCKS (NSAMP / 64)   // 2048: 64 samples per block (2 per 8-lane octet)

typedef float vfloat2 __attribute__((ext_vector_type(2)));

// ---------------------------------------------------------------------------
// fp8 e4m3 (OCP) pack/unpack via gfx950 HW converts.
// ---------------------------------------------------------------------------
__device__ __forceinline__ unsigned pack4_fp8(float f0, float f1, float f2, float f3)
{
    int r = __builtin_amdgcn_cvt_pk_fp8_f32(f0, f1, 0, false);  // bytes 0,1
    r     = __builtin_amdgcn_cvt_pk_fp8_f32(f2, f3, r, true);   // bytes 2,3
    return (unsigned)r;
}

// ---------------------------------------------------------------------------
// Kernel 1: batched transpose (B, C, S) fp32 -> (B, S, C) fp8 e4m3.
// 64x64 tile, float4 reads, LDS fp32 tile padded to 65 (<=2-way bank alias,
// free on gfx950), 4-byte packed fp8 writes.
// blockIdx.z: bit3 selects tensor, bits0..2 select batch.
// ---------------------------------------------------------------------------
__global__ __launch_bounds__(256) void transpose_to_bsc_fp8(
    const float* __restrict__ in0, const float* __restrict__ in1,
    unsigned char* __restrict__ out0, unsigned char* __restrict__ out1)
{
    __shared__ float tile[64][65];

    const int which = blockIdx.z >> 3;
    const int b     = blockIdx.z & 7;
    const float* __restrict__ in  = which ? in1 : in0;
    unsigned char* __restrict__ out = which ? out1 : out0;

    const int s0 = blockIdx.x * 64;
    const int c0 = blockIdx.y * 64;
    const int t  = threadIdx.x;

    const float* __restrict__ inb  = in  + (size_t)b * NC * NS;
    unsigned char* __restrict__ outb = out + (size_t)b * NS * NC;

    // ---- read: float4 along s, 16 c-rows per pass ----
    const int g   = t >> 4;          // 0..15
    const int sl4 = (t & 15) << 2;   // 0,4,...,60
#pragma unroll
    for (int pass = 0; pass < 4; ++pass) {
        const int cl = pass * 16 + g;
        const float4 v = *(const float4*)&inb[(size_t)(c0 + cl) * NS + (s0 + sl4)];
        tile[sl4 + 0][cl] = v.x;
        tile[sl4 + 1][cl] = v.y;
        tile[sl4 + 2][cl] = v.z;
        tile[sl4 + 3][cl] = v.w;
    }
    __syncthreads();

    // ---- write: 4 packed fp8 along c, 16 s-rows per pass ----
    const int cl4 = (t & 15) << 2;
#pragma unroll
    for (int pass = 0; pass < 4; ++pass) {
        const int sl = pass * 16 + (t >> 4);
        const unsigned w = pack4_fp8(tile[sl][cl4 + 0], tile[sl][cl4 + 1],
                                     tile[sl][cl4 + 2], tile[sl][cl4 + 3]);
        *(unsigned*)&outb[(size_t)(s0 + sl) * NC + (c0 + cl4)] = w;
    }
}

// ---------------------------------------------------------------------------
// Kernel 2: gather + triplet loss. TWO samples per 8-lane octet; 12
// independent 16B loads per thread issued before any use (MLP=12).
// Vector = 256 fp8 = 16 uint4; 8 lanes x 2 uint4 per vector.
// ---------------------------------------------------------------------------
__device__ __forceinline__ void acc_u32(unsigned a, unsigned p, unsigned n, float& d)
{
    const vfloat2 a0 = __builtin_amdgcn_cvt_pk_f32_fp8(a, false);
    const vfloat2 a1 = __builtin_amdgcn_cvt_pk_f32_fp8(a, true);
    const vfloat2 p0 = __builtin_amdgcn_cvt_pk_f32_fp8(p, false);
    const vfloat2 p1 = __builtin_amdgcn_cvt_pk_f32_fp8(p, true);
    const vfloat2 n0 = __builtin_amdgcn_cvt_pk_f32_fp8(n, false);
    const vfloat2 n1 = __builtin_amdgcn_cvt_pk_f32_fp8(n, true);
    float t;
    t = a0.x - p0.x; d += t * t;  t = a0.x - n0.x; d -= t * t;
    t = a0.y - p0.y; d += t * t;  t = a0.y - n0.y; d -= t * t;
    t = a1.x - p1.x; d += t * t;  t = a1.x - n1.x; d -= t * t;
    t = a1.y - p1.y; d += t * t;  t = a1.y - n1.y; d -= t * t;
}

__device__ __forceinline__ void acc_quad(uint4 a, uint4 p, uint4 n, float& d)
{
    acc_u32(a.x, p.x, n.x, d);
    acc_u32(a.y, p.y, n.y, d);
    acc_u32(a.z, p.z, n.z, d);
    acc_u32(a.w, p.w, n.w, d);
}

__device__ __forceinline__ size_t vec_base(int b, int2 yx)
{
    return ((size_t)(b * NS) + yx.x * FW + yx.y) * 16;   // uint4 units
}

__global__ __launch_bounds__(256) void triplet_gather_fp8(
    const uint4* __restrict__ tq,   // (B*S) vectors, 16 uint4 each
    const uint4* __restrict__ tk,
    const int*  __restrict__ batch_idx,
    const int2* __restrict__ anchor_yx,
    const int2* __restrict__ pos_yx,
    const int2* __restrict__ neg_yx,
    float* __restrict__ out)
{
    const int t    = threadIdx.x;
    const int ol   = t & 7;          // lane within octet
    const int oct  = t >> 3;         // octet id within block, 0..31
    const int sA   = blockIdx.x * 64 + oct;        // first sample
    const int sB   = sA + 32;                      // second sample

    const int  bA  = batch_idx[sA];
    const int  bB  = batch_idx[sB];
    const int2 ayA = anchor_yx[sA];
    const int2 ayB = anchor_yx[sB];
    const int2 pyA = pos_yx[sA];
    const int2 pyB = pos_yx[sB];
    const int2 nyA = neg_yx[sA];
    const int2 nyB = neg_yx[sB];

    const size_t abA = vec_base(bA, ayA);
    const size_t pbA = vec_base(bA, pyA);
    const size_t nbA = vec_base(bA, nyA);
    const size_t abB = vec_base(bB, ayB);
    const size_t pbB = vec_base(bB, pyB);
    const size_t nbB = vec_base(bB, nyB);

    // 12 independent loads, all issued before any use.
    const uint4 A0a = tq[abA + ol];
    const uint4 A1a = tq[abA + 8 + ol];
    const uint4 P0a = tk[pbA + ol];
    const uint4 P1a = tk[pbA + 8 + ol];
    const uint4 N0a = tk[nbA + ol];
    const uint4 N1a = tk[nbA + 8 + ol];
    const uint4 A0b = tq[abB + ol];
    const uint4 A1b = tq[abB + 8 + ol];
    const uint4 P0b = tk[pbB + ol];
    const uint4 P1b = tk[pbB + 8 + ol];
    const uint4 N0b = tk[nbB + ol];
    const uint4 N1b = tk[nbB + 8 + ol];

    float dA = 0.0f, dB = 0.0f;
    acc_quad(A0a, P0a, N0a, dA);
    acc_quad(A1a, P1a, N1a, dA);
    acc_quad(A0b, P0b, N0b, dB);
    acc_quad(A1b, P1b, N1b, dB);

    // reduce both across the 8-lane octet
#pragma unroll
    for (int m = 1; m < 8; m <<= 1) {
        dA += __shfl_xor(dA, m, 64);
        dB += __shfl_xor(dB, m, 64);
    }

    __shared__ float part[32];
    if (ol == 0) part[oct] = fmaxf(dA + MARGIN_F, 0.0f) + fmaxf(dB + MARGIN_F, 0.0f);
    __syncthreads();
    if (t == 0) {
        float s = 0.0f;
#pragma unroll
        for (int i = 0; i < 32; ++i) s += part[i];
        const float invN = 1.0f / (1e-6f + (float)NSAMP);
        atomicAdd(out, s * invN);
    }
}

// ---------------------------------------------------------------------------
// Fallback (ws too small): direct strided gather in original layout.
// ---------------------------------------------------------------------------
__global__ __launch_bounds__(256) void triplet_direct(
    const float* __restrict__ q, const float* __restrict__ k,
    const int*  __restrict__ batch_idx,
    const int2* __restrict__ anchor_yx,
    const int2* __restrict__ pos_yx,
    const int2* __restrict__ neg_yx,
    float* __restrict__ out)
{
    const int lane   = threadIdx.x & 63;
    const int wid    = threadIdx.x >> 6;
    const int gwave  = blockIdx.x * 4 + wid;
    const int nwaves = gridDim.x * 4;

    float wsum = 0.0f;
    for (int i = gwave; i < NSAMP; i += nwaves) {
        const int  b  = batch_idx[i];
        const int2 ay = anchor_yx[i];
        const int2 py = pos_yx[i];
        const int2 ny = neg_yx[i];

        const size_t base = (size_t)b * NC * NS;
        const int sa = ay.x * FW + ay.y;
        const int sp = py.x * FW + py.y;
        const int sn = ny.x * FW + ny.y;

        float d = 0.0f;
#pragma unroll
        for (int kk = 0; kk < 4; ++kk) {
            const int c = lane + 64 * kk;
            const float av = q[base + (size_t)c * NS + sa];
            const float pv = k[base + (size_t)c * NS + sp];
            const float nv = k[base + (size_t)c * NS + sn];
            float t;
            t = av - pv; d += t * t;
            t = av - nv; d -= t * t;
        }
#pragma unroll
        for (int m = 1; m < 64; m <<= 1) d += __shfl_xor(d, m, 64);
        if (lane == 0) wsum += fmaxf(d + MARGIN_F, 0.0f);
    }

    __shared__ float bsum[4];
    if (lane == 0) bsum[wid] = wsum;
    __syncthreads();
    if (threadIdx.x == 0) {
        const float invN = 1.0f / (1e-6f + (float)NSAMP);
        atomicAdd(out, (bsum[0] + bsum[1] + bsum[2] + bsum[3]) * invN);
    }
}

extern "C" void kernel_launch(void* const* d_in, const int* in_sizes, int n_in,
                              void* d_out, int out_size, void* d_ws, size_t ws_size,
                              hipStream_t stream)
{
    const float* sketch = (const float*)d_in[0];
    const float* refk   = (const float*)d_in[1];
    const int*   bidx   = (const int*)d_in[2];
    const int2*  ayx    = (const int2*)d_in[3];
    const int2*  pyx    = (const int2*)d_in[4];
    const int2*  nyx    = (const int2*)d_in[5];
    float*       out    = (float*)d_out;

    // zero the scalar accumulator (poisoned 0xAA)
    (void)hipMemsetAsync(out, 0, sizeof(float), stream);

    const size_t tensor_elems = (size_t)NB * NC * NS;             // 8M
    const size_t need = 2 * tensor_elems * sizeof(unsigned char); // 16 MB fp8

    if (ws_size >= need) {
        unsigned char* tq = (unsigned char*)d_ws;
        unsigned char* tk = tq + tensor_elems;

        dim3 tgrid(NS / 64, NC / 64, 16);   // 64 x 4 x 16
        transpose_to_bsc_fp8<<<tgrid, 256, 0, stream>>>(sketch, refk, tq, tk);

        triplet_gather_fp8<<<GATHER_BLOCKS, 256, 0, stream>>>(
            (const uint4*)tq, (const uint4*)tk, bidx, ayx, pyx, nyx, out);
    } else {
        triplet_direct<<<4096, 256, 0, stream>>>(
            sketch, refk, bidx, ayx, pyx, nyx, out);
    }
}